// Round 6
// baseline (207.232 us; speedup 1.0000x reference)
//
#include <hip/hip_runtime.h>
#include <hip/hip_bf16.h>

#define BATCH 64
#define UNITS 1024
#define CHUNK 16384

typedef unsigned int u32;
typedef unsigned short u16;

// ---------------- zero helper (fallback paths only) ------------------------
__global__ __launch_bounds__(256)
void zero4_kernel(uint4* __restrict__ p, int n4) {
    int i = blockIdx.x * 256 + threadIdx.x;
    const int stride = gridDim.x * 256;
    const uint4 z = make_uint4(0u, 0u, 0u, 0u);
    for (; i < n4; i += stride) p[i] = z;
}

// ---------------- transpose x[64][nfeat] f32 -> xT[nfeat][64] bf16 ---------
__global__ __launch_bounds__(256)
void transpose_x_kernel(const float* __restrict__ x, u16* __restrict__ xT,
                        int nfeat) {
    __shared__ float tile[64][65];
    const int c0 = blockIdx.x * 64;
    const int tx = threadIdx.x;             // 0..63
    const int ty = threadIdx.y;             // 0..3
    for (int b = ty; b < 64; b += 4) {
        int col = c0 + tx;
        if (col < nfeat) tile[b][tx] = x[(size_t)b * nfeat + col];
    }
    __syncthreads();
    for (int i = ty; i < 64; i += 4) {
        int col = c0 + i;
        if (col < nfeat) {
            __hip_bfloat16 h = __float2bfloat16(tile[tx][i]);
            xT[(size_t)col * 64 + tx] = *(u16*)&h;
        }
    }
}

// ---------------- pass 1: per-chunk histogram (NO global atomics) ----------
__global__ __launch_bounds__(256)
void hist_kernel(const int* __restrict__ col, u32* __restrict__ hist2, int nnz) {
    __shared__ u32 lh[UNITS];
    for (int i = threadIdx.x; i < UNITS; i += 256) lh[i] = 0u;
    __syncthreads();
    const int g0 = blockIdx.x * CHUNK;
    const int n = min(CHUNK, nnz - g0);
    for (int i = threadIdx.x; i < n; i += 256)
        atomicAdd(&lh[col[g0 + i]], 1u);
    __syncthreads();
    for (int c = threadIdx.x; c < UNITS; c += 256)
        hist2[(size_t)blockIdx.x * UNITS + c] = lh[c];
}

// ---------------- pass 2: column scan + per-chunk base matrix --------------
// col_start[c] = exclusive scan over columns of total counts.
// base2[g][c]  = col_start[c] + sum_{g'<g} hist2[g'][c]  (deterministic bases)
__global__ __launch_bounds__(1024)
void scan_kernel(const u32* __restrict__ hist2, u32* __restrict__ base2,
                 u32* __restrict__ col_start, int nchunk) {
    const int c = threadIdx.x;
    u32 tot = 0;
#pragma unroll 4
    for (int g = 0; g < nchunk; ++g) tot += hist2[(size_t)g * UNITS + c];
    __shared__ u32 a[UNITS];
    a[c] = tot;
    __syncthreads();
    for (int off = 1; off < UNITS; off <<= 1) {
        u32 add = (c >= off) ? a[c - off] : 0u;
        u32 v = a[c];
        __syncthreads();
        a[c] = v + add;
        __syncthreads();
    }
    const u32 excl = a[c] - tot;
    col_start[c] = excl;
    if (c == UNITS - 1) col_start[UNITS] = a[UNITS - 1];
    u32 run = excl;
    for (int g = 0; g < nchunk; ++g) {
        base2[(size_t)g * UNITS + c] = run;
        run += hist2[(size_t)g * UNITS + c];
    }
}

// ---------------- pass 3: reorder with precomputed bases -------------------
// Only LDS atomics (within-chunk rank); zero global atomics. 16-entry average
// runs per (WG,column) keep the 8B scatter writes line-local.
__global__ __launch_bounds__(512)
void reorder_kernel(const int* __restrict__ row, const int* __restrict__ col,
                    const float* __restrict__ w, const u32* __restrict__ base2,
                    uint2* __restrict__ sorted, int nnz) {
    __shared__ u32 cur[UNITS];
    const int tid = threadIdx.x;
    const int g = blockIdx.x;
    const int g0 = g * CHUNK;
    const int n = min(CHUNK, nnz - g0);
    for (int c = tid; c < UNITS; c += 512) cur[c] = base2[(size_t)g * UNITS + c];
    __syncthreads();
    if (n == CHUNK) {
        for (int j = 0; j < 32; j += 8) {
            u32 cc[8], rr[8], wb[8], lo[8];
#pragma unroll
            for (int q = 0; q < 8; ++q) {
                const int i = g0 + tid + 512 * (j + q);
                cc[q] = (u32)col[i];
                rr[q] = (u32)row[i];
                wb[q] = __float_as_uint(w[i]);
            }
#pragma unroll
            for (int q = 0; q < 8; ++q) lo[q] = atomicAdd(&cur[cc[q]], 1u);
#pragma unroll
            for (int q = 0; q < 8; ++q) sorted[lo[q]] = make_uint2(rr[q], wb[q]);
        }
    } else {
        for (int i = tid; i < n; i += 512) {
            const u32 c = (u32)col[g0 + i];
            const u32 lo = atomicAdd(&cur[c], 1u);
            sorted[lo] = make_uint2((u32)row[g0 + i], __float_as_uint(w[g0 + i]));
        }
    }
}

// ---------------- pass 4: per-column gather, batch-half split --------------
// HALF selects batches [HALF*32, HALF*32+32): hot xT lines = 3.2 MB, fits the
// 4 MB per-XCD L2. Lanes 0-31 process even entries, 32-63 odd entries; one
// global_load_ushort per pair covers 2 cache lines. (r,w) via readlane pairs
// (register/SALU only, no dependent index loads). Writes out[b][u] directly.
template<int HALF>
__global__ __launch_bounds__(256)
void gather_half_kernel(const u16* __restrict__ xTu, const uint2* __restrict__ sorted,
                        const u32* __restrict__ col_start, float* __restrict__ out) {
    const int u = blockIdx.x;
    const int tid = threadIdx.x;
    const int wv = tid >> 6;
    const int lane = tid & 63;
    const int sub = lane >> 5;          // even/odd entry of each pair
    const int bl = lane & 31;           // batch within half
    const u32 s = col_start[u], e = col_start[u + 1];
    const u16* base = xTu + HALF * 32 + bl;
    float acc[8] = {0.f, 0.f, 0.f, 0.f, 0.f, 0.f, 0.f, 0.f};
    for (u32 b0 = s + (u32)wv * 64u; b0 < e; b0 += 256u) {
        uint2 pk = make_uint2(0u, 0u);              // tail: w=0 -> no-op
        if (b0 + (u32)lane < e) pk = sorted[b0 + (u32)lane];
#pragma unroll
        for (int t2 = 0; t2 < 2; ++t2) {            // 2 groups of 16 pairs
            u32 rsel[16], wsel[16];
#pragma unroll
            for (int t = 0; t < 16; ++t) {
                const int p = t2 * 32 + 2 * t;
                const u32 r0 = (u32)__builtin_amdgcn_readlane((int)pk.x, p);
                const u32 r1 = (u32)__builtin_amdgcn_readlane((int)pk.x, p + 1);
                const u32 w0 = (u32)__builtin_amdgcn_readlane((int)pk.y, p);
                const u32 w1 = (u32)__builtin_amdgcn_readlane((int)pk.y, p + 1);
                rsel[t] = sub ? r1 : r0;
                wsel[t] = sub ? w1 : w0;
            }
            float xv[16];
#pragma unroll
            for (int t = 0; t < 16; ++t)
                xv[t] = __uint_as_float(((u32)base[(size_t)rsel[t] * 64]) << 16);
#pragma unroll
            for (int t = 0; t < 16; ++t)
                acc[t & 7] = fmaf(xv[t], __uint_as_float(wsel[t]), acc[t & 7]);
        }
    }
    float tot = ((acc[0] + acc[1]) + (acc[2] + acc[3])) +
                ((acc[4] + acc[5]) + (acc[6] + acc[7]));
    tot += __shfl_xor(tot, 32);          // combine even/odd sub-groups
    __shared__ float red[4][32];
    if (sub == 0) red[wv][bl] = tot;
    __syncthreads();
    if (tid < 32)
        out[(size_t)(HALF * 32 + tid) * UNITS + u] =
            red[0][tid] + red[1][tid] + red[2][tid] + red[3][tid];
}

// ---------------- small-ws fallbacks ---------------------------------------
__global__ __launch_bounds__(1024, 1)
void scatter_fallback_kernel(const u16* __restrict__ xT, const float* __restrict__ w,
                             const int* __restrict__ row_idx, const int* __restrict__ col_idx,
                             float* __restrict__ out, int nnz) {
    extern __shared__ float priv[];
    const int tid = threadIdx.x;
    for (int i = tid; i < 32 * UNITS; i += 1024) priv[i] = 0.0f;
    __syncthreads();
    const int bid = blockIdx.x, half = bid >> 7, wgIdx = bid & 127;
    const int wave = tid >> 6, lane = tid & 63, h = lane >> 5, bl = lane & 31;
    const int per = (nnz + 127) >> 7;
    const int k0 = wgIdx * per, kend = min(k0 + per, nnz);
    const u16* xTh = xT + half * 32 + bl;
    for (int k = k0 + wave * 2 + h; k < kend; k += 32) {
        const int r = row_idx[k], c = col_idx[k];
        const float xv = __uint_as_float(((u32)xTh[(size_t)r * 64]) << 16);
        atomicAdd(&priv[c * 32 + bl], xv * w[k]);
    }
    __syncthreads();
    for (int i = tid; i < 32 * UNITS; i += 1024) {
        int c = i >> 5, b = half * 32 + (i & 31);
        unsafeAtomicAdd(&out[b * UNITS + c], priv[i]);
    }
}

__global__ __launch_bounds__(256)
void fallback_kernel(const float* __restrict__ x, const float* __restrict__ w,
                     const int* __restrict__ row_idx, const int* __restrict__ col_idx,
                     float* __restrict__ out, int nnz, int nfeat) {
    const int nwaves = (gridDim.x * blockDim.x) >> 6;
    const int wid = (blockIdx.x * blockDim.x + threadIdx.x) >> 6;
    const int lane = threadIdx.x & 63;
    for (int k = wid; k < nnz; k += nwaves) {
        const int r = row_idx[k], c = col_idx[k];
        unsafeAtomicAdd(&out[lane * UNITS + c], x[(size_t)lane * nfeat + r] * w[k]);
    }
}

static inline size_t align256(size_t v) { return (v + 255) & ~(size_t)255; }

extern "C" void kernel_launch(void* const* d_in, const int* in_sizes, int n_in,
                              void* d_out, int out_size, void* d_ws, size_t ws_size,
                              hipStream_t stream) {
    const float* x       = (const float*)d_in[0];
    const float* w       = (const float*)d_in[1];
    const int*   row_idx = (const int*)d_in[2];
    const int*   col_idx = (const int*)d_in[3];
    float*       out     = (float*)d_out;
    const int    nnz     = in_sizes[1];
    const int    nfeat   = in_sizes[0] / BATCH;
    const int    nchunk  = (nnz + CHUNK - 1) / CHUNK;

    // ws layout
    const size_t xT_bytes = (size_t)nfeat * 64 * sizeof(u16);             // 6.4 MB
    size_t o = align256(xT_bytes);
    const size_t sorted_off = o;  o = align256(o + (size_t)nnz * sizeof(uint2));   // 16 MB
    const size_t hist2_off  = o;  o = align256(o + (size_t)nchunk * UNITS * sizeof(u32));
    const size_t base2_off  = o;  o = align256(o + (size_t)nchunk * UNITS * sizeof(u32));
    const size_t cs_off     = o;  o = align256(o + (UNITS + 1) * sizeof(u32));

    if (ws_size >= o) {
        u16*   xT        = (u16*)d_ws;
        uint2* sorted    = (uint2*)((char*)d_ws + sorted_off);
        u32*   hist2     = (u32*)((char*)d_ws + hist2_off);
        u32*   base2     = (u32*)((char*)d_ws + base2_off);
        u32*   col_start = (u32*)((char*)d_ws + cs_off);

        dim3 tb(64, 4);
        transpose_x_kernel<<<(nfeat + 63) / 64, tb, 0, stream>>>(x, xT, nfeat);
        hist_kernel<<<nchunk, 256, 0, stream>>>(col_idx, hist2, nnz);
        scan_kernel<<<1, 1024, 0, stream>>>(hist2, base2, col_start, nchunk);
        reorder_kernel<<<nchunk, 512, 0, stream>>>(
            row_idx, col_idx, w, base2, sorted, nnz);
        gather_half_kernel<0><<<UNITS, 256, 0, stream>>>(xT, sorted, col_start, out);
        gather_half_kernel<1><<<UNITS, 256, 0, stream>>>(xT, sorted, col_start, out);
    } else if (ws_size >= xT_bytes) {
        u16* xT = (u16*)d_ws;
        const int nOut4 = (out_size * 4 + 15) / 16;
        zero4_kernel<<<64, 256, 0, stream>>>((uint4*)out, nOut4);
        dim3 tb(64, 4);
        transpose_x_kernel<<<(nfeat + 63) / 64, tb, 0, stream>>>(x, xT, nfeat);
        scatter_fallback_kernel<<<256, 1024, 32 * UNITS * sizeof(float), stream>>>(
            xT, w, row_idx, col_idx, out, nnz);
    } else {
        const int nOut4 = (out_size * 4 + 15) / 16;
        zero4_kernel<<<64, 256, 0, stream>>>((uint4*)out, nOut4);
        fallback_kernel<<<2048, 256, 0, stream>>>(x, w, row_idx, col_idx, out, nnz, nfeat);
    }
}

// Round 7
// 140.088 us; speedup vs baseline: 1.4793x; 1.4793x over previous
//
#include <hip/hip_runtime.h>
#include <hip/hip_bf16.h>

#define BATCH 64
#define UNITS 1024
#define CHUNK 8192
#define JB 32          // chunks per scan block

typedef unsigned int u32;
typedef unsigned short u16;

// ---------------- zero helper (fallback paths only) ------------------------
__global__ __launch_bounds__(256)
void zero4_kernel(uint4* __restrict__ p, int n4) {
    int i = blockIdx.x * 256 + threadIdx.x;
    const int stride = gridDim.x * 256;
    const uint4 z = make_uint4(0u, 0u, 0u, 0u);
    for (; i < n4; i += stride) p[i] = z;
}

// ---------------- fused: transpose x -> bf16 xT  AND  per-chunk histogram --
// blocks [0, nT): transpose 64-col slab.  blocks [nT, nT+nchunk): histogram.
__global__ __launch_bounds__(256)
void prep_kernel(const float* __restrict__ x, u16* __restrict__ xT,
                 const int* __restrict__ col, u32* __restrict__ hist2,
                 int nfeat, int nT, int nnz) {
    __shared__ float tile[64][65];
    __shared__ u32 lh[UNITS];
    const int bid = blockIdx.x;
    const int tid = threadIdx.x;
    if (bid < nT) {
        const int c0 = bid * 64;
        const int tx = tid & 63, ty = tid >> 6;
        for (int b = ty; b < 64; b += 4) {
            int c = c0 + tx;
            if (c < nfeat) tile[b][tx] = x[(size_t)b * nfeat + c];   // coalesced
        }
        __syncthreads();
        for (int i = ty; i < 64; i += 4) {
            int c = c0 + i;
            if (c < nfeat) {
                __hip_bfloat16 h = __float2bfloat16(tile[tx][i]);
                xT[(size_t)c * 64 + tx] = *(u16*)&h;                 // coalesced
            }
        }
    } else {
        const int g = bid - nT;
        for (int i = tid; i < UNITS; i += 256) lh[i] = 0u;
        __syncthreads();
        const int g0 = g * CHUNK;
        const int n = min(CHUNK, nnz - g0);
        for (int i = tid; i < n; i += 256)
            atomicAdd(&lh[col[g0 + i]], 1u);
        __syncthreads();
        for (int c = tid; c < UNITS; c += 256)
            hist2[(size_t)g * UNITS + c] = lh[c];
    }
}

// ---------------- scanA: per-block-of-JB-chunks column partials ------------
__global__ __launch_bounds__(1024)
void scanA_kernel(const u32* __restrict__ hist2, u32* __restrict__ partial,
                  int nchunk) {
    const int j = blockIdx.x, c = threadIdx.x;
    const int gs = j * JB, ge = min(gs + JB, nchunk);
    u32 s = 0;
#pragma unroll 8
    for (int g = gs; g < ge; ++g) s += hist2[(size_t)g * UNITS + c];  // coalesced
    partial[(size_t)j * UNITS + c] = s;
}

// ---------------- scanB: column exclusive scan + per-block bases -----------
__global__ __launch_bounds__(1024)
void scanB_kernel(const u32* __restrict__ partial, u32* __restrict__ jb,
                  u32* __restrict__ col_start, int nblk) {
    const int c = threadIdx.x;
    u32 tot = 0;
    for (int j = 0; j < nblk; ++j) tot += partial[(size_t)j * UNITS + c];
    __shared__ u32 a[UNITS];
    a[c] = tot;
    __syncthreads();
    for (int off = 1; off < UNITS; off <<= 1) {
        u32 add = (c >= off) ? a[c - off] : 0u;
        u32 v = a[c];
        __syncthreads();
        a[c] = v + add;
        __syncthreads();
    }
    u32 run = a[c] - tot;                    // exclusive column prefix
    col_start[c] = run;
    if (c == UNITS - 1) col_start[UNITS] = a[UNITS - 1];
    for (int j = 0; j < nblk; ++j) {
        jb[(size_t)j * UNITS + c] = run;
        run += partial[(size_t)j * UNITS + c];
    }
}

// ---------------- reorder: pack (bf16(w)<<16 | row) into column bins -------
// Computes its own chunk base = jb[block] + sum of earlier hist2 rows in the
// block (<=31 coalesced loads, parallel across 245 WGs). LDS atomics only.
__global__ __launch_bounds__(512)
void reorder_kernel(const int* __restrict__ row, const int* __restrict__ col,
                    const float* __restrict__ w, const u32* __restrict__ hist2,
                    const u32* __restrict__ jb, u32* __restrict__ sorted, int nnz) {
    __shared__ u32 cur[UNITS];
    const int tid = threadIdx.x;
    const int g = blockIdx.x;
    const int j = g / JB, gs = j * JB;
    for (int c = tid; c < UNITS; c += 512) {
        u32 v = jb[(size_t)j * UNITS + c];
#pragma unroll 4
        for (int gp = gs; gp < g; ++gp) v += hist2[(size_t)gp * UNITS + c];
        cur[c] = v;
    }
    __syncthreads();
    const int g0 = g * CHUNK;
    const int n = min(CHUNK, nnz - g0);
#pragma unroll 4
    for (int i = tid; i < n; i += 512) {
        const int k = g0 + i;
        const u32 c = (u32)col[k];
        __hip_bfloat16 h = __float2bfloat16(w[k]);
        const u32 pk = ((u32)(*(const u16*)&h) << 16) | (u32)row[k];
        const u32 lo = atomicAdd(&cur[c], 1u);
        sorted[lo] = pk;                     // 4B scatter, ~8-entry runs/line
    }
}

// ---------------- gather: one column per WG, 64 batches = 64 lanes ---------
// readlane -> wave-uniform entry: row addressing folds to SALU + one
// v_lshl_add (SGPR src0); w bits already in f32-bf16 position (s_and).
// Per entry: ~4 VALU + 2 SALU + 1 global_load_ushort.
__global__ __launch_bounds__(256)
void gather_kernel(const u16* __restrict__ xTu, const u32* __restrict__ sorted,
                   const u32* __restrict__ col_start, float* __restrict__ out) {
    const int u = blockIdx.x;
    const int tid = threadIdx.x;
    const int wv = tid >> 6, lane = tid & 63;       // lane = batch
    const u32 s = col_start[u], e = col_start[u + 1];
    float acc0 = 0.f, acc1 = 0.f, acc2 = 0.f, acc3 = 0.f;
    for (u32 b0 = s + (u32)wv * 64u; b0 < e; b0 += 256u) {
        u32 pk = 0u;                                 // pad: w=+0 -> no-op
        if (b0 + (u32)lane < e) pk = sorted[b0 + (u32)lane];
#pragma unroll
        for (int t = 0; t < 64; t += 4) {
            const u32 e0 = (u32)__builtin_amdgcn_readlane((int)pk, t);
            const u32 e1 = (u32)__builtin_amdgcn_readlane((int)pk, t + 1);
            const u32 e2 = (u32)__builtin_amdgcn_readlane((int)pk, t + 2);
            const u32 e3 = (u32)__builtin_amdgcn_readlane((int)pk, t + 3);
            const float x0 = __uint_as_float(((u32)xTu[(size_t)(e0 & 0xffffu) * 64 + lane]) << 16);
            const float x1 = __uint_as_float(((u32)xTu[(size_t)(e1 & 0xffffu) * 64 + lane]) << 16);
            const float x2 = __uint_as_float(((u32)xTu[(size_t)(e2 & 0xffffu) * 64 + lane]) << 16);
            const float x3 = __uint_as_float(((u32)xTu[(size_t)(e3 & 0xffffu) * 64 + lane]) << 16);
            acc0 = fmaf(x0, __uint_as_float(e0 & 0xffff0000u), acc0);
            acc1 = fmaf(x1, __uint_as_float(e1 & 0xffff0000u), acc1);
            acc2 = fmaf(x2, __uint_as_float(e2 & 0xffff0000u), acc2);
            acc3 = fmaf(x3, __uint_as_float(e3 & 0xffff0000u), acc3);
        }
    }
    float tot = (acc0 + acc1) + (acc2 + acc3);
    __shared__ float red[4][64];
    red[wv][lane] = tot;
    __syncthreads();
    if (wv == 0)
        out[(size_t)lane * UNITS + u] =
            red[0][lane] + red[1][lane] + red[2][lane] + red[3][lane];
}

// ---------------- small-ws fallbacks ---------------------------------------
__global__ __launch_bounds__(1024, 1)
void scatter_fallback_kernel(const u16* __restrict__ xT, const float* __restrict__ w,
                             const int* __restrict__ row_idx, const int* __restrict__ col_idx,
                             float* __restrict__ out, int nnz) {
    extern __shared__ float priv[];
    const int tid = threadIdx.x;
    for (int i = tid; i < 32 * UNITS; i += 1024) priv[i] = 0.0f;
    __syncthreads();
    const int bid = blockIdx.x, half = bid >> 7, wgIdx = bid & 127;
    const int wave = tid >> 6, lane = tid & 63, h = lane >> 5, bl = lane & 31;
    const int per = (nnz + 127) >> 7;
    const int k0 = wgIdx * per, kend = min(k0 + per, nnz);
    const u16* xTh = xT + half * 32 + bl;
    for (int k = k0 + wave * 2 + h; k < kend; k += 32) {
        const int r = row_idx[k], c = col_idx[k];
        const float xv = __uint_as_float(((u32)xTh[(size_t)r * 64]) << 16);
        atomicAdd(&priv[c * 32 + bl], xv * w[k]);
    }
    __syncthreads();
    for (int i = tid; i < 32 * UNITS; i += 1024) {
        int c = i >> 5, b = half * 32 + (i & 31);
        unsafeAtomicAdd(&out[b * UNITS + c], priv[i]);
    }
}

__global__ __launch_bounds__(256)
void fallback_kernel(const float* __restrict__ x, const float* __restrict__ w,
                     const int* __restrict__ row_idx, const int* __restrict__ col_idx,
                     float* __restrict__ out, int nnz, int nfeat) {
    const int nwaves = (gridDim.x * blockDim.x) >> 6;
    const int wid = (blockIdx.x * blockDim.x + threadIdx.x) >> 6;
    const int lane = threadIdx.x & 63;
    for (int k = wid; k < nnz; k += nwaves) {
        const int r = row_idx[k], c = col_idx[k];
        unsafeAtomicAdd(&out[lane * UNITS + c], x[(size_t)lane * nfeat + r] * w[k]);
    }
}

static inline size_t align256(size_t v) { return (v + 255) & ~(size_t)255; }

extern "C" void kernel_launch(void* const* d_in, const int* in_sizes, int n_in,
                              void* d_out, int out_size, void* d_ws, size_t ws_size,
                              hipStream_t stream) {
    const float* x       = (const float*)d_in[0];
    const float* w       = (const float*)d_in[1];
    const int*   row_idx = (const int*)d_in[2];
    const int*   col_idx = (const int*)d_in[3];
    float*       out     = (float*)d_out;
    const int    nnz     = in_sizes[1];
    const int    nfeat   = in_sizes[0] / BATCH;
    const int    nchunk  = (nnz + CHUNK - 1) / CHUNK;
    const int    nblk    = (nchunk + JB - 1) / JB;
    const int    nT      = (nfeat + 63) / 64;

    // ws layout
    const size_t xT_bytes = (size_t)nfeat * 64 * sizeof(u16);                    // 6.4 MB
    size_t o = align256(xT_bytes);
    const size_t sorted_off = o;  o = align256(o + (size_t)nnz * sizeof(u32));   // 8 MB
    const size_t hist2_off  = o;  o = align256(o + (size_t)nchunk * UNITS * sizeof(u32));
    const size_t part_off   = o;  o = align256(o + (size_t)nblk * UNITS * sizeof(u32));
    const size_t jb_off     = o;  o = align256(o + (size_t)nblk * UNITS * sizeof(u32));
    const size_t cs_off     = o;  o = align256(o + (UNITS + 1) * sizeof(u32));

    if (ws_size >= o && nfeat <= 65536 && nblk <= 64) {
        u16* xT        = (u16*)d_ws;
        u32* sorted    = (u32*)((char*)d_ws + sorted_off);
        u32* hist2     = (u32*)((char*)d_ws + hist2_off);
        u32* partial   = (u32*)((char*)d_ws + part_off);
        u32* jb        = (u32*)((char*)d_ws + jb_off);
        u32* col_start = (u32*)((char*)d_ws + cs_off);

        prep_kernel<<<nT + nchunk, 256, 0, stream>>>(x, xT, col_idx, hist2,
                                                     nfeat, nT, nnz);
        scanA_kernel<<<nblk, 1024, 0, stream>>>(hist2, partial, nchunk);
        scanB_kernel<<<1, 1024, 0, stream>>>(partial, jb, col_start, nblk);
        reorder_kernel<<<nchunk, 512, 0, stream>>>(row_idx, col_idx, w, hist2,
                                                   jb, sorted, nnz);
        gather_kernel<<<UNITS, 256, 0, stream>>>(xT, sorted, col_start, out);
    } else if (ws_size >= xT_bytes) {
        u16* xT = (u16*)d_ws;
        const int nOut4 = (out_size * 4 + 15) / 16;
        zero4_kernel<<<64, 256, 0, stream>>>((uint4*)out, nOut4);
        dim3 tb(256);
        prep_kernel<<<nT, 256, 0, stream>>>(x, xT, col_idx, nullptr, nfeat, nT, 0);
        scatter_fallback_kernel<<<256, 1024, 32 * UNITS * sizeof(float), stream>>>(
            xT, w, row_idx, col_idx, out, nnz);
    } else {
        const int nOut4 = (out_size * 4 + 15) / 16;
        zero4_kernel<<<64, 256, 0, stream>>>((uint4*)out, nOut4);
        fallback_kernel<<<2048, 256, 0, stream>>>(x, w, row_idx, col_idx, out, nnz, nfeat);
    }
}